// Round 1
// baseline (200.438 us; speedup 1.0000x reference)
//
#include <hip/hip_runtime.h>
#include <hip/hip_bf16.h>

#define NB 8
#define N1 2048
#define N2 1152
#define KD 1024
#define BM 128
#define BN 144
#define BK 32

typedef __attribute__((ext_vector_type(8))) short bf16x8;
typedef __attribute__((ext_vector_type(4))) float f32x4;

__device__ __forceinline__ unsigned short f2bf_rne(float f) {
  union { float f; unsigned u; } c; c.f = f;
  unsigned u = c.u;
  u += 0x7FFFu + ((u >> 16) & 1u);
  return (unsigned short)(u >> 16);
}

// One block per row (K=1024): convert fp32 -> bf16 and compute row squared norm.
__global__ __launch_bounds__(256) void convert_kernel(
    const float* __restrict__ x1, const float* __restrict__ x2,
    unsigned short* __restrict__ x1b, unsigned short* __restrict__ x2b,
    float* __restrict__ sq1, float* __restrict__ sq2) {
  int row = blockIdx.x;
  const float* src;
  unsigned short* dst;
  float* sqp;
  if (row < NB * N1) {
    src = x1 + (size_t)row * KD;
    dst = x1b + (size_t)row * KD;
    sqp = sq1 + row;
  } else {
    int r = row - NB * N1;
    src = x2 + (size_t)r * KD;
    dst = x2b + (size_t)r * KD;
    sqp = sq2 + r;
  }
  int t = threadIdx.x;  // 256 threads x float4 = 1024 elements = one row
  float4 v = ((const float4*)src)[t];
  ushort4 o;
  o.x = f2bf_rne(v.x);
  o.y = f2bf_rne(v.y);
  o.z = f2bf_rne(v.z);
  o.w = f2bf_rne(v.w);
  ((ushort4*)dst)[t] = o;
  float s = v.x * v.x + v.y * v.y + v.z * v.z + v.w * v.w;
#pragma unroll
  for (int off = 32; off > 0; off >>= 1) s += __shfl_down(s, off);
  __shared__ float red[4];
  int lane = t & 63, wave = t >> 6;
  if (lane == 0) red[wave] = s;
  __syncthreads();
  if (t == 0) *sqp = red[0] + red[1] + red[2] + red[3];
}

__device__ __forceinline__ void async_copy16(const void* g, void* l) {
  __builtin_amdgcn_global_load_lds(
      (const __attribute__((address_space(1))) unsigned int*)g,
      (__attribute__((address_space(3))) unsigned int*)l, 16, 0, 0);
}

// Fused distance + group-min(9) + mean kernel.
// Block tile: 128 (M=x1 rows) x 144 (N=x2 rows). 144 = 16 MFMA cols tiles... = 16 groups of 9.
// 4 waves, each owns 32 M-rows (2 MFMA row-tiles) x full 144 cols (9 col-tiles).
__global__ __launch_bounds__(256) void dist_kernel(
    const unsigned short* __restrict__ x1b, const unsigned short* __restrict__ x2b,
    const float* __restrict__ sq1, const float* __restrict__ sq2,
    float* __restrict__ out) {
  // staging: A tile 128x32 bf16 (8192 B) + B tile 144x32 bf16 (9216 B) = 17408 B
  // epilogue: 64x144 fp32 chunk = 36864 B (union)
  __shared__ __align__(16) char smem[64 * BN * 4];

  const int tid = threadIdx.x;
  const int wave = tid >> 6, lane = tid & 63;
  const int bm = blockIdx.x, bn = blockIdx.y, b = blockIdx.z;

  const unsigned short* Ag = x1b + ((size_t)b * N1 + bm * BM) * KD;
  const unsigned short* Bg = x2b + ((size_t)b * N2 + bn * BN) * KD;

  const int l4r = lane >> 2;        // staging: row within 16-row chunk
  const int l4c = (lane & 3) * 8;   // staging: element offset within 32-wide K slab
  const int quad = lane >> 4;       // 0..3
  const int fr = lane & 15;         // fragment row (A) / col (B,D)
  const int qk = quad * 8;          // fragment k offset

  f32x4 acc[2][9];
#pragma unroll
  for (int i = 0; i < 2; ++i)
#pragma unroll
    for (int j = 0; j < 9; ++j) {
      f32x4 z = {0.f, 0.f, 0.f, 0.f};
      acc[i][j] = z;
    }

  for (int k0 = 0; k0 < KD; k0 += BK) {
    // 17 chunks of 1 KB: chunks 0..7 = A tile, 8..16 = B tile (laid out at smem+8192..)
    for (int j = wave; j < 17; j += 4) {
      if (j < 8) {
        const unsigned short* g = Ag + (size_t)(j * 16 + l4r) * KD + k0 + l4c;
        async_copy16(g, smem + j * 1024 + lane * 16);
      } else {
        const unsigned short* g = Bg + (size_t)((j - 8) * 16 + l4r) * KD + k0 + l4c;
        async_copy16(g, smem + j * 1024 + lane * 16);
      }
    }
    __syncthreads();  // drains vmcnt (global_load_lds) before LDS reads

    bf16x8 a0 = *(const bf16x8*)(smem + ((wave * 32 + fr) * BK + qk) * 2);
    bf16x8 a1 = *(const bf16x8*)(smem + ((wave * 32 + 16 + fr) * BK + qk) * 2);
#pragma unroll
    for (int tn = 0; tn < 9; ++tn) {
      bf16x8 bF = *(const bf16x8*)(smem + 8192 + ((tn * 16 + fr) * BK + qk) * 2);
      acc[0][tn] = __builtin_amdgcn_mfma_f32_16x16x32_bf16(a0, bF, acc[0][tn], 0, 0, 0);
      acc[1][tn] = __builtin_amdgcn_mfma_f32_16x16x32_bf16(a1, bF, acc[1][tn], 0, 0, 0);
    }
    __syncthreads();  // before next stage overwrites LDS
  }

  // ---- epilogue: d = sq1 + sq2 - 2*cross, min over groups of 9 cols, sum ----
  float s2[9];
#pragma unroll
  for (int tn = 0; tn < 9; ++tn)
    s2[tn] = sq2[(size_t)b * N2 + bn * BN + tn * 16 + fr];

  float s1v[2][4];
#pragma unroll
  for (int tm = 0; tm < 2; ++tm)
#pragma unroll
    for (int r = 0; r < 4; ++r)
      s1v[tm][r] = sq1[(size_t)b * N1 + bm * BM + wave * 32 + tm * 16 + quad * 4 + r];

  float* eps = (float*)smem;
  float local = 0.f;
#pragma unroll
  for (int tm = 0; tm < 2; ++tm) {
    __syncthreads();  // previous chunk (or K-loop LDS) fully consumed
    // D layout (16x16x32): col = lane&15, row = quad*4 + reg
#pragma unroll
    for (int tn = 0; tn < 9; ++tn)
#pragma unroll
      for (int r = 0; r < 4; ++r)
        eps[(wave * 16 + quad * 4 + r) * BN + tn * 16 + fr] =
            s1v[tm][r] + s2[tn] - 2.0f * acc[tm][tn][r];
    __syncthreads();
    // 64 rows x 16 groups = 1024 groups, 4 per thread
#pragma unroll
    for (int q = 0; q < 4; ++q) {
      int g = tid + q * 256;
      int row = g >> 4, grp = g & 15;
      const float* p = eps + row * BN + grp * 9;
      float mn = p[0];
#pragma unroll
      for (int jj = 1; jj < 9; ++jj) mn = fminf(mn, p[jj]);
      local += mn;
    }
  }

  // block reduction -> scaled atomicAdd
#pragma unroll
  for (int off = 32; off > 0; off >>= 1) local += __shfl_down(local, off);
  __syncthreads();
  if (lane == 0) eps[wave] = local;
  __syncthreads();
  if (tid == 0) {
    float s = eps[0] + eps[1] + eps[2] + eps[3];
    // total group count = 8 * 2048 * 1152 / 9 = 2097152
    atomicAdd(out, s * (1.0f / 2097152.0f));
  }
}

extern "C" void kernel_launch(void* const* d_in, const int* in_sizes, int n_in,
                              void* d_out, int out_size, void* d_ws, size_t ws_size,
                              hipStream_t stream) {
  const float* x1 = (const float*)d_in[0];
  const float* x2 = (const float*)d_in[1];
  char* ws = (char*)d_ws;
  const size_t x1b_bytes = (size_t)NB * N1 * KD * 2;  // 33554432
  const size_t x2b_bytes = (size_t)NB * N2 * KD * 2;  // 18874368
  unsigned short* x1b = (unsigned short*)ws;
  unsigned short* x2b = (unsigned short*)(ws + x1b_bytes);
  float* sq1 = (float*)(ws + x1b_bytes + x2b_bytes);
  float* sq2 = (float*)(ws + x1b_bytes + x2b_bytes + (size_t)NB * N1 * 4);

  hipMemsetAsync(d_out, 0, sizeof(float), stream);
  convert_kernel<<<NB * (N1 + N2), 256, 0, stream>>>(x1, x2, x1b, x2b, sq1, sq2);
  dist_kernel<<<dim3(N1 / BM, N2 / BN, NB), 256, 0, stream>>>(x1b, x2b, sq1, sq2,
                                                              (float*)d_out);
}